// Round 10
// baseline (264.903 us; speedup 1.0000x reference)
//
#include <hip/hip_runtime.h>
#include <math.h>

#define B_ 2
#define S_ 2048
#define D_ 1024
#define H_ 16
#define DH_ 64

typedef _Float16 f16;
typedef _Float16 f16x8 __attribute__((ext_vector_type(8)));
typedef _Float16 f16x4 __attribute__((ext_vector_type(4)));
typedef __fp16 fp16x2 __attribute__((ext_vector_type(2)));
typedef float f32x4 __attribute__((ext_vector_type(4)));

#define MFMA16(a, b, c) __builtin_amdgcn_mfma_f32_16x16x32_f16(a, b, c, 0, 0, 0)

// DPP cross-lane move on VALU pipe (row = 16 lanes on CDNA).
#define DPPF(x, ctrl) \
    __int_as_float(__builtin_amdgcn_mov_dpp(__float_as_int(x), (ctrl), 0xF, 0xF, true))

// k-slot permutation within each 32-column V tile: position p holds
// k = (p>>1) + 16*(p&1)  (pairs (k, k+16) adjacent -> b32 P writes).
__device__ __forceinline__ int permc(int c) {
    return (c & 32) | ((c & 15) << 1) | ((c >> 4) & 1);
}

// ---------------------------------------------------------------------------
// W [k][n] fp32  ->  Wht/Wlt [n][k] f16 hi/lo (transposed, 3 weights via z)
// ---------------------------------------------------------------------------
__global__ __launch_bounds__(256) void split_w_kernel(
    const float* __restrict__ Wq, const float* __restrict__ Wk,
    const float* __restrict__ Wv, f16* __restrict__ wht, f16* __restrict__ wlt)
{
    __shared__ float T[64][69];
    const float* W = (blockIdx.z == 0) ? Wq : (blockIdx.z == 1) ? Wk : Wv;
    f16* ht = wht + (size_t)blockIdx.z * D_ * D_;
    f16* lt = wlt + (size_t)blockIdx.z * D_ * D_;
    const int t  = threadIdx.x;
    const int k0 = blockIdx.x * 64;
    const int n0 = blockIdx.y * 64;

#pragma unroll
    for (int it = 0; it < 4; ++it) {
        int idx = t + it * 256;
        int row = idx >> 4;
        int c4  = (idx & 15) * 4;
        float4 v = *reinterpret_cast<const float4*>(&W[(size_t)(k0 + row) * D_ + n0 + c4]);
        T[row][c4 + 0] = v.x; T[row][c4 + 1] = v.y;
        T[row][c4 + 2] = v.z; T[row][c4 + 3] = v.w;
    }
    __syncthreads();
#pragma unroll
    for (int it = 0; it < 4; ++it) {
        int idx = t + it * 256;
        int nl = idx >> 4;
        int kc = (idx & 15) * 4;
        f16x4 h4, l4;
#pragma unroll
        for (int j = 0; j < 4; ++j) {
            float v = T[kc + j][nl];
            f16 h = (f16)v;
            h4[j] = h;
            l4[j] = (f16)(v - (float)h);
        }
        size_t base = (size_t)(n0 + nl) * D_ + k0 + kc;
        *reinterpret_cast<f16x4*>(&ht[base]) = h4;
        *reinterpret_cast<f16x4*>(&lt[base]) = l4;
    }
}

// ---------------------------------------------------------------------------
// dist fp32 [4095][64] -> pe f16 [4096][64] (row 4095 duplicates 4094 so the
// attention band's unused corner reads stay in-bounds).
// ---------------------------------------------------------------------------
__global__ __launch_bounds__(256) void pe_convert_kernel(
    const float* __restrict__ dist, f16* __restrict__ pe)
{
    int i = blockIdx.x * 256 + threadIdx.x;       // float4 index, 4096*16 total
    if (i < 4096 * 16) {
        int src = (i < 4095 * 16) ? i : (i - 16);
        float4 v = reinterpret_cast<const float4*>(dist)[src];
        f16x4 o = {(f16)v.x, (f16)v.y, (f16)v.z, (f16)v.w};
        *reinterpret_cast<f16x4*>(&pe[(size_t)i * 4]) = o;
    }
}

// ---------------------------------------------------------------------------
// MFMA QKV projection, 2-term split (ah*wh + ah*wl).
// Q,K: f16 [B,H,S,64]. V: f16 transposed [B,H,64,S], k-slot permuted.
// ---------------------------------------------------------------------------
__global__ __launch_bounds__(256) void mfma_proj_kernel(
    const float* __restrict__ A,
    const f16* __restrict__ wht, const f16* __restrict__ wlt,
    const float* __restrict__ bq, const float* __restrict__ bk,
    const float* __restrict__ bv,
    f16* __restrict__ qh, f16* __restrict__ kh,
    f16* __restrict__ vt)
{
    __shared__ __align__(16) f16 SM[18432];          // 36 KB
    f16* Ah = SM;                                     // [128][40]
    f16* Wh = SM + 5120;
    f16* Wl = SM + 10240;

    const int z = blockIdx.z;
    const f16* wh_g = wht + (size_t)z * D_ * D_;
    const f16* wl_g = wlt + (size_t)z * D_ * D_;
    const float* bias = (z == 0) ? bq : (z == 1) ? bk : bv;

    const int t    = threadIdx.x;
    const int w    = t >> 6;
    const int lane = t & 63;
    const int lo   = lane & 15;
    const int g    = lane >> 4;
    const int wrow = w >> 1;
    const int wcol = w & 1;
    const int m0   = blockIdx.x * 128;
    const int n0   = blockIdx.y * 128;

    f32x4 acc[4][4];
#pragma unroll
    for (int i = 0; i < 4; ++i)
#pragma unroll
        for (int j = 0; j < 4; ++j) acc[i][j] = (f32x4){0.f, 0.f, 0.f, 0.f};

    for (int k0 = 0; k0 < D_; k0 += 32) {
        __syncthreads();
#pragma unroll
        for (int it = 0; it < 4; ++it) {
            int idx = t + it * 256;
            int row = idx >> 3;
            int c   = idx & 7;
            float4 v = *reinterpret_cast<const float4*>(
                &A[(size_t)(m0 + row) * D_ + k0 + c * 4]);
            f16x4 h4 = {(f16)v.x, (f16)v.y, (f16)v.z, (f16)v.w};
            *reinterpret_cast<f16x4*>(&Ah[row * 40 + c * 4]) = h4;
        }
#pragma unroll
        for (int it = 0; it < 2; ++it) {
            int idx = t + it * 256;
            int row = idx >> 2;
            int c   = idx & 3;
            size_t gsrc = (size_t)(n0 + row) * D_ + k0 + c * 8;
            *reinterpret_cast<f16x8*>(&Wh[row * 40 + c * 8]) =
                *reinterpret_cast<const f16x8*>(&wh_g[gsrc]);
            *reinterpret_cast<f16x8*>(&Wl[row * 40 + c * 8]) =
                *reinterpret_cast<const f16x8*>(&wl_g[gsrc]);
        }
        __syncthreads();

        f16x8 ah[4], whf[4], wlf[4];
#pragma unroll
        for (int m = 0; m < 4; ++m) {
            int row = wrow * 64 + m * 16 + lo;
            ah[m] = *reinterpret_cast<const f16x8*>(&Ah[row * 40 + g * 8]);
        }
#pragma unroll
        for (int n = 0; n < 4; ++n) {
            int row = wcol * 64 + n * 16 + lo;
            whf[n] = *reinterpret_cast<const f16x8*>(&Wh[row * 40 + g * 8]);
            wlf[n] = *reinterpret_cast<const f16x8*>(&Wl[row * 40 + g * 8]);
        }
#pragma unroll
        for (int m = 0; m < 4; ++m)
#pragma unroll
            for (int n = 0; n < 4; ++n) {
                acc[m][n] = MFMA16(ah[m], whf[n], acc[m][n]);
                acc[m][n] = MFMA16(ah[m], wlf[n], acc[m][n]);
            }
    }

    float bias_v[4];
#pragma unroll
    for (int n = 0; n < 4; ++n) bias_v[n] = bias[n0 + wcol * 64 + n * 16 + lo];

    if (z < 2) {
        f16* hd = (z == 0) ? qh : kh;
#pragma unroll
        for (int n = 0; n < 4; ++n) {
            int col = n0 + wcol * 64 + n * 16 + lo;
            int hh  = col >> 6;
            int dh  = col & 63;
#pragma unroll
            for (int m = 0; m < 4; ++m)
#pragma unroll
                for (int r = 0; r < 4; ++r) {
                    int grow = m0 + wrow * 64 + m * 16 + g * 4 + r;
                    int bb   = grow >> 11;
                    int ss   = grow & (S_ - 1);
                    float val = acc[m][n][r] + bias_v[n];
                    size_t base = ((size_t)(bb * H_ + hh) * S_ + ss) * DH_ + dh;
                    hd[base] = (f16)val;
                }
        }
    } else {
        __syncthreads();
        f16* vtile = SM + w * 4608;           // [64][72]
#pragma unroll
        for (int n = 0; n < 4; ++n)
#pragma unroll
            for (int m = 0; m < 4; ++m)
#pragma unroll
                for (int r = 0; r < 4; ++r) {
                    int c = m * 16 + g * 4 + r;
                    vtile[(n * 16 + lo) * 72 + permc(c)] =
                        (f16)(acc[m][n][r] + bias_v[n]);
                }
        int bb = m0 >> 11;
        int s_base = (m0 & (S_ - 1)) + wrow * 64;
#pragma unroll
        for (int it = 0; it < 8; ++it) {
            int idx = lane + it * 64;
            int cl  = idx >> 3;
            int mc  = idx & 7;
            f16x8 vv = *reinterpret_cast<const f16x8*>(&vtile[cl * 72 + mc * 8]);
            int col = n0 + wcol * 64 + cl;
            int hh  = col >> 6;
            int dh  = col & 63;
            *reinterpret_cast<f16x8*>(
                &vt[((size_t)(bb * H_ + hh) * DH_ + dh) * S_ + s_base + mc * 8]) = vv;
        }
    }
}

// ---------------------------------------------------------------------------
// MFMA flash attention, v7: PE fragments read straight from global (L2/L3
// resident, shared by all heads), double-buffered K/V (1 barrier/iter),
// q-tile 32/wave, packed-pair P publish, fixed-shift softmax.
// ---------------------------------------------------------------------------
__global__ __launch_bounds__(256) void attn_mfma_kernel(
    const f16* __restrict__ qh, const f16* __restrict__ kh,
    const f16* __restrict__ vt, const f16* __restrict__ pe,
    const float* __restrict__ gm, const float* __restrict__ am,
    float* __restrict__ out)
{
    __shared__ __align__(16) f16 Kh[2][32 * 72];
    __shared__ __align__(16) f16 Vt[2][64 * 40];
    __shared__ __align__(16) f16 Pl[4 * 32 * 40];

    const int t    = threadIdx.x;
    const int w    = t >> 6;
    const int lane = t & 63;
    const int lo   = lane & 15;
    const int g    = lane >> 4;
    const int bh   = blockIdx.y;
    const int b    = bh >> 4;
    const int h    = bh & 15;
    const int l0   = blockIdx.x * 128;
    const int lw   = l0 + w * 32;

    const int krow = t >> 3, kc8 = (t & 7) * 8;       // K staging pattern
    const int vrow = t >> 2, vc8 = (t & 3) * 8;       // V staging pattern

    // Q fragments for both 16-row subs
    f16x8 qf[2][2];
#pragma unroll
    for (int sub = 0; sub < 2; ++sub) {
        size_t qbase = ((size_t)bh * S_ + lw + sub * 16 + lo) * DH_ + g * 8;
        qf[sub][0] = *reinterpret_cast<const f16x8*>(qh + qbase);
        qf[sub][1] = *reinterpret_cast<const f16x8*>(qh + qbase + 32);
    }

    // iter-0 staging: load + write buf 0
    f16x8 kreg, vreg;
    kreg = *reinterpret_cast<const f16x8*>(kh + ((size_t)bh * S_ + krow) * DH_ + kc8);
    vreg = *reinterpret_cast<const f16x8*>(vt + ((size_t)bh * DH_ + vrow) * S_ + vc8);
    *reinterpret_cast<f16x8*>(Kh[0] + krow * 72 + kc8) = kreg;
    *reinterpret_cast<f16x8*>(Vt[0] + vrow * 40 + vc8) = vreg;

    f32x4 o[2][4];
#pragma unroll
    for (int sub = 0; sub < 2; ++sub)
#pragma unroll
        for (int n = 0; n < 4; ++n) o[sub][n] = (f32x4){0.f, 0.f, 0.f, 0.f};
    float l_part[2][4] = {{0.f, 0.f, 0.f, 0.f}, {0.f, 0.f, 0.f, 0.f}};

    f16* Pw = Pl + w * 32 * 40;

    for (int r0 = 0; r0 < S_; r0 += 32) {
        const int p  = (r0 >> 5) & 1;
        const int g0 = l0 + 2016 - r0;
        __syncthreads();                       // buf p valid; buf p^1 free

        // issue next tile's staging loads (hide under this iter's compute)
        if (r0 + 32 < S_) {
            int r0n = r0 + 32;
            kreg = *reinterpret_cast<const f16x8*>(
                kh + ((size_t)bh * S_ + r0n + krow) * DH_ + kc8);
            vreg = *reinterpret_cast<const f16x8*>(
                vt + ((size_t)bh * DH_ + vrow) * S_ + r0n + vc8);
        }
        // PE band fragments straight from global (L2-resident)
        f16x8 pef[4][2];
#pragma unroll
        for (int tau = 0; tau < 4; ++tau) {
            const f16* pb = pe + (size_t)(g0 + w * 32 + tau * 16 + lo) * DH_ + g * 8;
            pef[tau][0] = *reinterpret_cast<const f16x8*>(pb);
            pef[tau][1] = *reinterpret_cast<const f16x8*>(pb + 32);
        }
        float am0 = am[b * S_ + r0 + lo];
        float am1 = am[b * S_ + r0 + 16 + lo];

        // ---- QK^T: K frags shared across subs ----
        const f16* khp = Kh[p];
        const f16* vtp = Vt[p];
        f32x4 sc[2][2];
        sc[0][0] = (f32x4){0.f,0.f,0.f,0.f}; sc[0][1] = (f32x4){0.f,0.f,0.f,0.f};
        sc[1][0] = (f32x4){0.f,0.f,0.f,0.f}; sc[1][1] = (f32x4){0.f,0.f,0.f,0.f};
#pragma unroll
        for (int u = 0; u < 2; ++u)
#pragma unroll
            for (int s = 0; s < 2; ++s) {
                f16x8 kb = *reinterpret_cast<const f16x8*>(
                    khp + (u * 16 + lo) * 72 + s * 32 + g * 8);
                sc[0][u] = MFMA16(qf[0][s], kb, sc[0][u]);
                sc[1][u] = MFMA16(qf[1][s], kb, sc[1][u]);
            }
        // ---- bias band: 4 tiles (sub0: 0-2, sub1: 1-3) ----
        f32x4 mmA[3], mmB[3];
#pragma unroll
        for (int i = 0; i < 3; ++i) {
            mmA[i] = (f32x4){0.f,0.f,0.f,0.f};
            mmB[i] = (f32x4){0.f,0.f,0.f,0.f};
        }
#pragma unroll
        for (int tau = 0; tau < 4; ++tau)
#pragma unroll
            for (int s = 0; s < 2; ++s) {
                if (tau < 3) mmA[tau]     = MFMA16(qf[0][s], pef[tau][s], mmA[tau]);
                if (tau > 0) mmB[tau - 1] = MFMA16(qf[1][s], pef[tau][s], mmB[tau - 1]);
            }
        // ---- scores + gather + fixed-shift exp + packed P publish ----
#pragma unroll
        for (int sub = 0; sub < 2; ++sub) {
            float gm0[4], gm1[4];
#pragma unroll
            for (int r = 0; r < 4; ++r) {
                size_t grow = (size_t)(lw + sub * 16 + g * 4 + r) * S_ + r0;
                gm0[r] = gm[grow + lo];
                gm1[r] = gm[grow + 16 + lo];
            }
#pragma unroll
            for (int r = 0; r < 4; ++r) {
                int dl = g * 4 + r;
                int pl_ = (dl + 15 - lo) & 15;
                bool cond = pl_ < dl;
                float v0, v1;
                if (sub == 0) {
                    v0 = cond ? mmA[2][r] : mmA[1][r];
                    v1 = cond ? mmA[1][r] : mmA[0][r];
                } else {
                    v0 = cond ? mmB[2][r] : mmB[1][r];
                    v1 = cond ? mmB[1][r] : mmB[0][r];
                }
                union { fp16x2 hv; int iv; } pk, gk;
                pk.hv = __builtin_amdgcn_cvt_pkrtz(v0, v1);
                int src = (lane & 48) | pl_;
                gk.iv = __shfl(pk.iv, src, 64);
                float s0 = (sc[sub][0][r] + (float)gk.hv[0]) * 0.125f * gm0[r] + am0;
                float s1 = (sc[sub][1][r] + (float)gk.hv[1]) * 0.125f * gm1[r] + am1;
                float p0 = __expf(s0 - 6.f);
                float p1 = __expf(s1 - 6.f);
                l_part[sub][r] += p0 + p1;
                union { f16 h2[2]; int iv; } pp;
                pp.h2[0] = (f16)p0;
                pp.h2[1] = (f16)p1;
                *reinterpret_cast<int*>(Pw + (sub * 16 + dl) * 40 + 2 * lo) = pp.iv;
            }
        }
        // ---- PV: V frags shared across subs ----
        f16x8 pa0 = *reinterpret_cast<const f16x8*>(Pw + lo * 40 + g * 8);
        f16x8 pa1 = *reinterpret_cast<const f16x8*>(Pw + (16 + lo) * 40 + g * 8);
#pragma unroll
        for (int n = 0; n < 4; ++n) {
            f16x8 vb = *reinterpret_cast<const f16x8*>(vtp + (n * 16 + lo) * 40 + g * 8);
            o[0][n] = MFMA16(pa0, vb, o[0][n]);
            o[1][n] = MFMA16(pa1, vb, o[1][n]);
        }
        // ---- write next tile's staged regs into the other buffer ----
        if (r0 + 32 < S_) {
            *reinterpret_cast<f16x8*>(Kh[p ^ 1] + krow * 72 + kc8) = kreg;
            *reinterpret_cast<f16x8*>(Vt[p ^ 1] + vrow * 40 + vc8) = vreg;
        }
    }

    // ---- epilogue ----
#pragma unroll
    for (int sub = 0; sub < 2; ++sub)
#pragma unroll
        for (int r = 0; r < 4; ++r) {
            float ls = l_part[sub][r];
            ls += DPPF(ls, 0xB1);
            ls += DPPF(ls, 0x4E);
            ls += DPPF(ls, 0x141);
            ls += DPPF(ls, 0x140);
            float inv = 1.f / ls;
            int l = lw + sub * 16 + g * 4 + r;
#pragma unroll
            for (int n = 0; n < 4; ++n)
                out[((size_t)b * S_ + l) * D_ + h * DH_ + n * 16 + lo] = o[sub][n][r] * inv;
        }
}

// ---------------------------------------------------------------------------
extern "C" void kernel_launch(void* const* d_in, const int* in_sizes, int n_in,
                              void* d_out, int out_size, void* d_ws, size_t ws_size,
                              hipStream_t stream)
{
    const float* hs    = (const float*)d_in[0];
    const float* amask = (const float*)d_in[1];
    const float* gmask = (const float*)d_in[2];
    const float* Wq    = (const float*)d_in[3];
    const float* bq    = (const float*)d_in[4];
    const float* Wk    = (const float*)d_in[5];
    const float* bk    = (const float*)d_in[6];
    const float* Wv    = (const float*)d_in[7];
    const float* bv    = (const float*)d_in[8];
    const float* dist  = (const float*)d_in[9];
    float* out = (float*)d_out;

    const size_t per = (size_t)B_ * H_ * S_ * DH_;   // 4M f16
    f16* qh  = (f16*)d_ws;
    f16* kh  = qh + per;
    f16* vt  = kh + per;
    f16* wht = vt + per;                              // 3M f16
    f16* wlt = wht + (size_t)3 * D_ * D_;             // 3M f16
    f16* pe  = wlt + (size_t)3 * D_ * D_;             // 4096*64 f16

    split_w_kernel<<<dim3(16, 16, 3), 256, 0, stream>>>(Wq, Wk, Wv, wht, wlt);
    pe_convert_kernel<<<dim3(256), 256, 0, stream>>>(dist, pe);

    dim3 g1((B_ * S_) / 128, D_ / 128, 3);
    mfma_proj_kernel<<<g1, 256, 0, stream>>>(hs, wht, wlt, bq, bk, bv,
                                             qh, kh, vt);

    dim3 g2(S_ / 128, B_ * H_);
    attn_mfma_kernel<<<g2, 256, 0, stream>>>(qh, kh, vt, pe,
                                             gmask, amask, out);
}

// Round 11
// 212.886 us; speedup vs baseline: 1.2443x; 1.2443x over previous
//
#include <hip/hip_runtime.h>
#include <math.h>

#define B_ 2
#define S_ 2048
#define D_ 1024
#define H_ 16
#define DH_ 64

typedef _Float16 f16;
typedef _Float16 f16x8 __attribute__((ext_vector_type(8)));
typedef _Float16 f16x4 __attribute__((ext_vector_type(4)));
typedef __fp16 fp16x2 __attribute__((ext_vector_type(2)));
typedef float f32x4 __attribute__((ext_vector_type(4)));

#define MFMA16(a, b, c) __builtin_amdgcn_mfma_f32_16x16x32_f16(a, b, c, 0, 0, 0)

// DPP cross-lane move on VALU pipe (row = 16 lanes on CDNA).
#define DPPF(x, ctrl) \
    __int_as_float(__builtin_amdgcn_mov_dpp(__float_as_int(x), (ctrl), 0xF, 0xF, true))

// k-slot permutation within each 32-column V tile: position p holds
// k = (p>>1) + 16*(p&1)  (pairs (k, k+16) adjacent -> b32 P writes).
__device__ __forceinline__ int permc(int c) {
    return (c & 32) | ((c & 15) << 1) | ((c >> 4) & 1);
}

// ---------------------------------------------------------------------------
// W [k][n] fp32  ->  Wht/Wlt [n][k] f16 hi/lo (transposed, 3 weights via z)
// ---------------------------------------------------------------------------
__global__ __launch_bounds__(256) void split_w_kernel(
    const float* __restrict__ Wq, const float* __restrict__ Wk,
    const float* __restrict__ Wv, f16* __restrict__ wht, f16* __restrict__ wlt)
{
    __shared__ float T[64][69];
    const float* W = (blockIdx.z == 0) ? Wq : (blockIdx.z == 1) ? Wk : Wv;
    f16* ht = wht + (size_t)blockIdx.z * D_ * D_;
    f16* lt = wlt + (size_t)blockIdx.z * D_ * D_;
    const int t  = threadIdx.x;
    const int k0 = blockIdx.x * 64;
    const int n0 = blockIdx.y * 64;

#pragma unroll
    for (int it = 0; it < 4; ++it) {
        int idx = t + it * 256;
        int row = idx >> 4;
        int c4  = (idx & 15) * 4;
        float4 v = *reinterpret_cast<const float4*>(&W[(size_t)(k0 + row) * D_ + n0 + c4]);
        T[row][c4 + 0] = v.x; T[row][c4 + 1] = v.y;
        T[row][c4 + 2] = v.z; T[row][c4 + 3] = v.w;
    }
    __syncthreads();
#pragma unroll
    for (int it = 0; it < 4; ++it) {
        int idx = t + it * 256;
        int nl = idx >> 4;
        int kc = (idx & 15) * 4;
        f16x4 h4, l4;
#pragma unroll
        for (int j = 0; j < 4; ++j) {
            float v = T[kc + j][nl];
            f16 h = (f16)v;
            h4[j] = h;
            l4[j] = (f16)(v - (float)h);
        }
        size_t base = (size_t)(n0 + nl) * D_ + k0 + kc;
        *reinterpret_cast<f16x4*>(&ht[base]) = h4;
        *reinterpret_cast<f16x4*>(&lt[base]) = l4;
    }
}

// ---------------------------------------------------------------------------
// dist fp32 [4095][64] -> pe f16 [4096][64] (row 4095 dups 4094; band corner
// reads stay in-bounds).
// ---------------------------------------------------------------------------
__global__ __launch_bounds__(256) void pe_convert_kernel(
    const float* __restrict__ dist, f16* __restrict__ pe)
{
    int i = blockIdx.x * 256 + threadIdx.x;       // float4 index, 4096*16 total
    if (i < 4096 * 16) {
        int src = (i < 4095 * 16) ? i : (i - 16);
        float4 v = reinterpret_cast<const float4*>(dist)[src];
        f16x4 o = {(f16)v.x, (f16)v.y, (f16)v.z, (f16)v.w};
        *reinterpret_cast<f16x4*>(&pe[(size_t)i * 4]) = o;
    }
}

// ---------------------------------------------------------------------------
// MFMA QKV projection, 2-term split (ah*wh + ah*wl).
// Q,K: f16 [B,H,S,64]. V: f16 transposed [B,H,64,S], k-slot permuted.
// ---------------------------------------------------------------------------
__global__ __launch_bounds__(256) void mfma_proj_kernel(
    const float* __restrict__ A,
    const f16* __restrict__ wht, const f16* __restrict__ wlt,
    const float* __restrict__ bq, const float* __restrict__ bk,
    const float* __restrict__ bv,
    f16* __restrict__ qh, f16* __restrict__ kh,
    f16* __restrict__ vt)
{
    __shared__ __align__(16) f16 SM[18432];          // 36 KB
    f16* Ah = SM;                                     // [128][40]
    f16* Wh = SM + 5120;
    f16* Wl = SM + 10240;

    const int z = blockIdx.z;
    const f16* wh_g = wht + (size_t)z * D_ * D_;
    const f16* wl_g = wlt + (size_t)z * D_ * D_;
    const float* bias = (z == 0) ? bq : (z == 1) ? bk : bv;

    const int t    = threadIdx.x;
    const int w    = t >> 6;
    const int lane = t & 63;
    const int lo   = lane & 15;
    const int g    = lane >> 4;
    const int wrow = w >> 1;
    const int wcol = w & 1;
    const int m0   = blockIdx.x * 128;
    const int n0   = blockIdx.y * 128;

    f32x4 acc[4][4];
#pragma unroll
    for (int i = 0; i < 4; ++i)
#pragma unroll
        for (int j = 0; j < 4; ++j) acc[i][j] = (f32x4){0.f, 0.f, 0.f, 0.f};

    for (int k0 = 0; k0 < D_; k0 += 32) {
        __syncthreads();
#pragma unroll
        for (int it = 0; it < 4; ++it) {
            int idx = t + it * 256;
            int row = idx >> 3;
            int c   = idx & 7;
            float4 v = *reinterpret_cast<const float4*>(
                &A[(size_t)(m0 + row) * D_ + k0 + c * 4]);
            f16x4 h4 = {(f16)v.x, (f16)v.y, (f16)v.z, (f16)v.w};
            *reinterpret_cast<f16x4*>(&Ah[row * 40 + c * 4]) = h4;
        }
#pragma unroll
        for (int it = 0; it < 2; ++it) {
            int idx = t + it * 256;
            int row = idx >> 2;
            int c   = idx & 3;
            size_t gsrc = (size_t)(n0 + row) * D_ + k0 + c * 8;
            *reinterpret_cast<f16x8*>(&Wh[row * 40 + c * 8]) =
                *reinterpret_cast<const f16x8*>(&wh_g[gsrc]);
            *reinterpret_cast<f16x8*>(&Wl[row * 40 + c * 8]) =
                *reinterpret_cast<const f16x8*>(&wl_g[gsrc]);
        }
        __syncthreads();

        f16x8 ah[4], whf[4], wlf[4];
#pragma unroll
        for (int m = 0; m < 4; ++m) {
            int row = wrow * 64 + m * 16 + lo;
            ah[m] = *reinterpret_cast<const f16x8*>(&Ah[row * 40 + g * 8]);
        }
#pragma unroll
        for (int n = 0; n < 4; ++n) {
            int row = wcol * 64 + n * 16 + lo;
            whf[n] = *reinterpret_cast<const f16x8*>(&Wh[row * 40 + g * 8]);
            wlf[n] = *reinterpret_cast<const f16x8*>(&Wl[row * 40 + g * 8]);
        }
#pragma unroll
        for (int m = 0; m < 4; ++m)
#pragma unroll
            for (int n = 0; n < 4; ++n) {
                acc[m][n] = MFMA16(ah[m], whf[n], acc[m][n]);
                acc[m][n] = MFMA16(ah[m], wlf[n], acc[m][n]);
            }
    }

    float bias_v[4];
#pragma unroll
    for (int n = 0; n < 4; ++n) bias_v[n] = bias[n0 + wcol * 64 + n * 16 + lo];

    if (z < 2) {
        f16* hd = (z == 0) ? qh : kh;
#pragma unroll
        for (int n = 0; n < 4; ++n) {
            int col = n0 + wcol * 64 + n * 16 + lo;
            int hh  = col >> 6;
            int dh  = col & 63;
#pragma unroll
            for (int m = 0; m < 4; ++m)
#pragma unroll
                for (int r = 0; r < 4; ++r) {
                    int grow = m0 + wrow * 64 + m * 16 + g * 4 + r;
                    int bb   = grow >> 11;
                    int ss   = grow & (S_ - 1);
                    float val = acc[m][n][r] + bias_v[n];
                    size_t base = ((size_t)(bb * H_ + hh) * S_ + ss) * DH_ + dh;
                    hd[base] = (f16)val;
                }
        }
    } else {
        __syncthreads();
        f16* vtile = SM + w * 4608;           // [64][72]
#pragma unroll
        for (int n = 0; n < 4; ++n)
#pragma unroll
            for (int m = 0; m < 4; ++m)
#pragma unroll
                for (int r = 0; r < 4; ++r) {
                    int c = m * 16 + g * 4 + r;
                    vtile[(n * 16 + lo) * 72 + permc(c)] =
                        (f16)(acc[m][n][r] + bias_v[n]);
                }
        int bb = m0 >> 11;
        int s_base = (m0 & (S_ - 1)) + wrow * 64;
#pragma unroll
        for (int it = 0; it < 8; ++it) {
            int idx = lane + it * 64;
            int cl  = idx >> 3;
            int mc  = idx & 7;
            f16x8 vv = *reinterpret_cast<const f16x8*>(&vtile[cl * 72 + mc * 8]);
            int col = n0 + wcol * 64 + cl;
            int hh  = col >> 6;
            int dh  = col & 63;
            *reinterpret_cast<f16x8*>(
                &vt[((size_t)(bb * H_ + hh) * DH_ + dh) * S_ + s_base + mc * 8]) = vv;
        }
    }
}

// ---------------------------------------------------------------------------
// MFMA flash attention, v8: R9 data layout (LDS PE ring, reg-staged K/V) with
// SINGLE barrier/iter — K/V double-buffered, PE ring writes one iter ahead
// (rows g0-32 ≡ g0+224 mod 256, disjoint from read window [g0, g0+159]),
// Pw wave-private. s_setprio around MFMA clusters (T5).
// ---------------------------------------------------------------------------
__global__ __launch_bounds__(256) void attn_mfma_kernel(
    const f16* __restrict__ qh, const f16* __restrict__ kh,
    const f16* __restrict__ vt, const f16* __restrict__ pe,
    const float* __restrict__ gm, const float* __restrict__ am,
    float* __restrict__ out)
{
    __shared__ __align__(16) f16 Kh[2][32 * 72];
    __shared__ __align__(16) f16 Vt[2][64 * 40];
    __shared__ __align__(16) f16 PE[256 * 72];
    __shared__ __align__(16) f16 Pl[4 * 32 * 40];

    const int t    = threadIdx.x;
    const int w    = t >> 6;
    const int lane = t & 63;
    const int lo   = lane & 15;
    const int g    = lane >> 4;
    const int bh   = blockIdx.y;
    const int b    = bh >> 4;
    const int h    = bh & 15;
    const int l0   = blockIdx.x * 128;
    const int lw   = l0 + w * 32;

    const int krow = t >> 3, kc8 = (t & 7) * 8;       // K & PE staging pattern
    const int vrow = t >> 2, vc8 = (t & 3) * 8;       // V staging pattern

    // Q fragments for both 16-row subs
    f16x8 qf[2][2];
#pragma unroll
    for (int sub = 0; sub < 2; ++sub) {
        size_t qbase = ((size_t)bh * S_ + lw + sub * 16 + lo) * DH_ + g * 8;
        qf[sub][0] = *reinterpret_cast<const f16x8*>(qh + qbase);
        qf[sub][1] = *reinterpret_cast<const f16x8*>(qh + qbase + 32);
    }

    // PE prefill: full initial window [l0+2016, l0+2176) (160 rows, clamped)
#pragma unroll
    for (int i = 0; i < 5; ++i) {
        int idx = t + i * 256;
        int row = idx >> 3, c8 = (idx & 7) * 8;
        int logical = l0 + 2016 + row;
        int gl = logical > 4094 ? 4094 : logical;
        *reinterpret_cast<f16x8*>(PE + (size_t)(logical & 255) * 72 + c8) =
            *reinterpret_cast<const f16x8*>(pe + (size_t)gl * DH_ + c8);
    }
    // iter-0 K/V: load + write buf 0
    {
        f16x8 k0r = *reinterpret_cast<const f16x8*>(
            kh + ((size_t)bh * S_ + krow) * DH_ + kc8);
        f16x8 v0r = *reinterpret_cast<const f16x8*>(
            vt + ((size_t)bh * DH_ + vrow) * S_ + vc8);
        *reinterpret_cast<f16x8*>(Kh[0] + krow * 72 + kc8) = k0r;
        *reinterpret_cast<f16x8*>(Vt[0] + vrow * 40 + vc8) = v0r;
    }

    f32x4 o[2][4];
#pragma unroll
    for (int sub = 0; sub < 2; ++sub)
#pragma unroll
        for (int n = 0; n < 4; ++n) o[sub][n] = (f32x4){0.f, 0.f, 0.f, 0.f};
    float l_part[2][4] = {{0.f, 0.f, 0.f, 0.f}, {0.f, 0.f, 0.f, 0.f}};

    f16* Pw = Pl + w * 32 * 40;

    for (int r0 = 0; r0 < S_; r0 += 32) {
        const int p  = (r0 >> 5) & 1;
        const int g0 = l0 + 2016 - r0;
        __syncthreads();                 // this iter's bufs + ring rows ready

        // issue next tile's staging loads (complete under this iter's compute)
        f16x8 kreg, vreg, pereg;
        const bool more = (r0 + 32 < S_);
        if (more) {
            int r0n = r0 + 32;
            kreg  = *reinterpret_cast<const f16x8*>(
                kh + ((size_t)bh * S_ + r0n + krow) * DH_ + kc8);
            vreg  = *reinterpret_cast<const f16x8*>(
                vt + ((size_t)bh * DH_ + vrow) * S_ + r0n + vc8);
            pereg = *reinterpret_cast<const f16x8*>(
                pe + (size_t)(g0 - 32 + krow) * DH_ + kc8);
        }
        float am0 = am[b * S_ + r0 + lo];
        float am1 = am[b * S_ + r0 + 16 + lo];

        const f16* khp = Kh[p];
        const f16* vtp = Vt[p];

        // ---- QK^T + bias band MFMA cluster ----
        __builtin_amdgcn_s_setprio(1);
        f32x4 sc[2][2];
        sc[0][0] = (f32x4){0.f,0.f,0.f,0.f}; sc[0][1] = (f32x4){0.f,0.f,0.f,0.f};
        sc[1][0] = (f32x4){0.f,0.f,0.f,0.f}; sc[1][1] = (f32x4){0.f,0.f,0.f,0.f};
#pragma unroll
        for (int u = 0; u < 2; ++u)
#pragma unroll
            for (int s = 0; s < 2; ++s) {
                f16x8 kb = *reinterpret_cast<const f16x8*>(
                    khp + (u * 16 + lo) * 72 + s * 32 + g * 8);
                sc[0][u] = MFMA16(qf[0][s], kb, sc[0][u]);
                sc[1][u] = MFMA16(qf[1][s], kb, sc[1][u]);
            }
        f32x4 mmA[3], mmB[3];
#pragma unroll
        for (int i = 0; i < 3; ++i) {
            mmA[i] = (f32x4){0.f,0.f,0.f,0.f};
            mmB[i] = (f32x4){0.f,0.f,0.f,0.f};
        }
#pragma unroll
        for (int tau = 0; tau < 4; ++tau) {
            int prow = (g0 + w * 32 + tau * 16 + lo) & 255;
#pragma unroll
            for (int s = 0; s < 2; ++s) {
                f16x8 pb = *reinterpret_cast<const f16x8*>(
                    PE + (size_t)prow * 72 + s * 32 + g * 8);
                if (tau < 3) mmA[tau]     = MFMA16(qf[0][s], pb, mmA[tau]);
                if (tau > 0) mmB[tau - 1] = MFMA16(qf[1][s], pb, mmB[tau - 1]);
            }
        }
        __builtin_amdgcn_s_setprio(0);

        // ---- scores + gather + fixed-shift exp + packed P publish ----
#pragma unroll
        for (int sub = 0; sub < 2; ++sub) {
            float gm0[4], gm1[4];
#pragma unroll
            for (int r = 0; r < 4; ++r) {
                size_t grow = (size_t)(lw + sub * 16 + g * 4 + r) * S_ + r0;
                gm0[r] = gm[grow + lo];
                gm1[r] = gm[grow + 16 + lo];
            }
#pragma unroll
            for (int r = 0; r < 4; ++r) {
                int dl = g * 4 + r;
                int pl_ = (dl + 15 - lo) & 15;
                bool cond = pl_ < dl;
                float v0, v1;
                if (sub == 0) {
                    v0 = cond ? mmA[2][r] : mmA[1][r];
                    v1 = cond ? mmA[1][r] : mmA[0][r];
                } else {
                    v0 = cond ? mmB[2][r] : mmB[1][r];
                    v1 = cond ? mmB[1][r] : mmB[0][r];
                }
                union { fp16x2 hv; int iv; } pk, gk;
                pk.hv = __builtin_amdgcn_cvt_pkrtz(v0, v1);
                int src = (lane & 48) | pl_;
                gk.iv = __shfl(pk.iv, src, 64);
                float s0 = (sc[sub][0][r] + (float)gk.hv[0]) * 0.125f * gm0[r] + am0;
                float s1 = (sc[sub][1][r] + (float)gk.hv[1]) * 0.125f * gm1[r] + am1;
                float p0 = __expf(s0 - 6.f);
                float p1 = __expf(s1 - 6.f);
                l_part[sub][r] += p0 + p1;
                union { f16 h2[2]; int iv; } pp;
                pp.h2[0] = (f16)p0;
                pp.h2[1] = (f16)p1;
                *reinterpret_cast<int*>(Pw + (sub * 16 + dl) * 40 + 2 * lo) = pp.iv;
            }
        }
        // ---- PV cluster (Pw wave-private; lgkmcnt ordering automatic) ----
        f16x8 pa0 = *reinterpret_cast<const f16x8*>(Pw + lo * 40 + g * 8);
        f16x8 pa1 = *reinterpret_cast<const f16x8*>(Pw + (16 + lo) * 40 + g * 8);
        __builtin_amdgcn_s_setprio(1);
#pragma unroll
        for (int n = 0; n < 4; ++n) {
            f16x8 vb = *reinterpret_cast<const f16x8*>(vtp + (n * 16 + lo) * 40 + g * 8);
            o[0][n] = MFMA16(pa0, vb, o[0][n]);
            o[1][n] = MFMA16(pa1, vb, o[1][n]);
        }
        __builtin_amdgcn_s_setprio(0);

        // ---- write next tile into the other buffer + ring rows g0-32 ----
        if (more) {
            *reinterpret_cast<f16x8*>(Kh[p ^ 1] + krow * 72 + kc8) = kreg;
            *reinterpret_cast<f16x8*>(Vt[p ^ 1] + vrow * 40 + vc8) = vreg;
            *reinterpret_cast<f16x8*>(
                PE + (size_t)((g0 - 32 + krow) & 255) * 72 + kc8) = pereg;
        }
    }

    // ---- epilogue ----
#pragma unroll
    for (int sub = 0; sub < 2; ++sub)
#pragma unroll
        for (int r = 0; r < 4; ++r) {
            float ls = l_part[sub][r];
            ls += DPPF(ls, 0xB1);
            ls += DPPF(ls, 0x4E);
            ls += DPPF(ls, 0x141);
            ls += DPPF(ls, 0x140);
            float inv = 1.f / ls;
            int l = lw + sub * 16 + g * 4 + r;
#pragma unroll
            for (int n = 0; n < 4; ++n)
                out[((size_t)b * S_ + l) * D_ + h * DH_ + n * 16 + lo] = o[sub][n][r] * inv;
        }
}

// ---------------------------------------------------------------------------
extern "C" void kernel_launch(void* const* d_in, const int* in_sizes, int n_in,
                              void* d_out, int out_size, void* d_ws, size_t ws_size,
                              hipStream_t stream)
{
    const float* hs    = (const float*)d_in[0];
    const float* amask = (const float*)d_in[1];
    const float* gmask = (const float*)d_in[2];
    const float* Wq    = (const float*)d_in[3];
    const float* bq    = (const float*)d_in[4];
    const float* Wk    = (const float*)d_in[5];
    const float* bk    = (const float*)d_in[6];
    const float* Wv    = (const float*)d_in[7];
    const float* bv    = (const float*)d_in[8];
    const float* dist  = (const float*)d_in[9];
    float* out = (float*)d_out;

    const size_t per = (size_t)B_ * H_ * S_ * DH_;   // 4M f16
    f16* qh  = (f16*)d_ws;
    f16* kh  = qh + per;
    f16* vt  = kh + per;
    f16* wht = vt + per;                              // 3M f16
    f16* wlt = wht + (size_t)3 * D_ * D_;             // 3M f16
    f16* pe  = wlt + (size_t)3 * D_ * D_;             // 4096*64 f16

    split_w_kernel<<<dim3(16, 16, 3), 256, 0, stream>>>(Wq, Wk, Wv, wht, wlt);
    pe_convert_kernel<<<dim3(1024), 256, 0, stream>>>(dist, pe);

    dim3 g1((B_ * S_) / 128, D_ / 128, 3);
    mfma_proj_kernel<<<g1, 256, 0, stream>>>(hs, wht, wlt, bq, bk, bv,
                                             qh, kh, vt);

    dim3 g2(S_ / 128, B_ * H_);
    attn_mfma_kernel<<<g2, 256, 0, stream>>>(qh, kh, vt, pe,
                                             gmask, amask, out);
}

// Round 12
// 195.520 us; speedup vs baseline: 1.3549x; 1.0888x over previous
//
#include <hip/hip_runtime.h>
#include <math.h>

#define B_ 2
#define S_ 2048
#define D_ 1024
#define H_ 16
#define DH_ 64

typedef _Float16 f16;
typedef _Float16 f16x8 __attribute__((ext_vector_type(8)));
typedef _Float16 f16x4 __attribute__((ext_vector_type(4)));
typedef __fp16 fp16x2 __attribute__((ext_vector_type(2)));
typedef float f32x4 __attribute__((ext_vector_type(4)));

#define MFMA16(a, b, c) __builtin_amdgcn_mfma_f32_16x16x32_f16(a, b, c, 0, 0, 0)

// DPP cross-lane move on VALU pipe (row = 16 lanes on CDNA).
#define DPPF(x, ctrl) \
    __int_as_float(__builtin_amdgcn_mov_dpp(__float_as_int(x), (ctrl), 0xF, 0xF, true))

// k-slot permutation within each 32-column V tile: position p holds
// k = (p>>1) + 16*(p&1)  (pairs (k, k+16) adjacent -> b32 P writes).
__device__ __forceinline__ int permc(int c) {
    return (c & 32) | ((c & 15) << 1) | ((c >> 4) & 1);
}

// ---------------------------------------------------------------------------
// W [k][n] fp32  ->  Wht/Wlt [n][k] f16 hi/lo (transposed, 3 weights via z)
// ---------------------------------------------------------------------------
__global__ __launch_bounds__(256) void split_w_kernel(
    const float* __restrict__ Wq, const float* __restrict__ Wk,
    const float* __restrict__ Wv, f16* __restrict__ wht, f16* __restrict__ wlt)
{
    __shared__ float T[64][69];
    const float* W = (blockIdx.z == 0) ? Wq : (blockIdx.z == 1) ? Wk : Wv;
    f16* ht = wht + (size_t)blockIdx.z * D_ * D_;
    f16* lt = wlt + (size_t)blockIdx.z * D_ * D_;
    const int t  = threadIdx.x;
    const int k0 = blockIdx.x * 64;
    const int n0 = blockIdx.y * 64;

#pragma unroll
    for (int it = 0; it < 4; ++it) {
        int idx = t + it * 256;
        int row = idx >> 4;
        int c4  = (idx & 15) * 4;
        float4 v = *reinterpret_cast<const float4*>(&W[(size_t)(k0 + row) * D_ + n0 + c4]);
        T[row][c4 + 0] = v.x; T[row][c4 + 1] = v.y;
        T[row][c4 + 2] = v.z; T[row][c4 + 3] = v.w;
    }
    __syncthreads();
#pragma unroll
    for (int it = 0; it < 4; ++it) {
        int idx = t + it * 256;
        int nl = idx >> 4;
        int kc = (idx & 15) * 4;
        f16x4 h4, l4;
#pragma unroll
        for (int j = 0; j < 4; ++j) {
            float v = T[kc + j][nl];
            f16 h = (f16)v;
            h4[j] = h;
            l4[j] = (f16)(v - (float)h);
        }
        size_t base = (size_t)(n0 + nl) * D_ + k0 + kc;
        *reinterpret_cast<f16x4*>(&ht[base]) = h4;
        *reinterpret_cast<f16x4*>(&lt[base]) = l4;
    }
}

// ---------------------------------------------------------------------------
// dist fp32 [4095][64] -> pe f16 [4096][64] (row 4095 dups 4094).
// ---------------------------------------------------------------------------
__global__ __launch_bounds__(256) void pe_convert_kernel(
    const float* __restrict__ dist, f16* __restrict__ pe)
{
    int i = blockIdx.x * 256 + threadIdx.x;       // float4 index, 4096*16 total
    if (i < 4096 * 16) {
        int src = (i < 4095 * 16) ? i : (i - 16);
        float4 v = reinterpret_cast<const float4*>(dist)[src];
        f16x4 o = {(f16)v.x, (f16)v.y, (f16)v.z, (f16)v.w};
        *reinterpret_cast<f16x4*>(&pe[(size_t)i * 4]) = o;
    }
}

// ---------------------------------------------------------------------------
// MFMA QKV projection, 2-term split (ah*wh + ah*wl).
// Q,K: f16 [B,H,S,64]. V: f16 transposed [B,H,64,S], k-slot permuted.
// ---------------------------------------------------------------------------
__global__ __launch_bounds__(256) void mfma_proj_kernel(
    const float* __restrict__ A,
    const f16* __restrict__ wht, const f16* __restrict__ wlt,
    const float* __restrict__ bq, const float* __restrict__ bk,
    const float* __restrict__ bv,
    f16* __restrict__ qh, f16* __restrict__ kh,
    f16* __restrict__ vt)
{
    __shared__ __align__(16) f16 SM[18432];          // 36 KB
    f16* Ah = SM;                                     // [128][40]
    f16* Wh = SM + 5120;
    f16* Wl = SM + 10240;

    const int z = blockIdx.z;
    const f16* wh_g = wht + (size_t)z * D_ * D_;
    const f16* wl_g = wlt + (size_t)z * D_ * D_;
    const float* bias = (z == 0) ? bq : (z == 1) ? bk : bv;

    const int t    = threadIdx.x;
    const int w    = t >> 6;
    const int lane = t & 63;
    const int lo   = lane & 15;
    const int g    = lane >> 4;
    const int wrow = w >> 1;
    const int wcol = w & 1;
    const int m0   = blockIdx.x * 128;
    const int n0   = blockIdx.y * 128;

    f32x4 acc[4][4];
#pragma unroll
    for (int i = 0; i < 4; ++i)
#pragma unroll
        for (int j = 0; j < 4; ++j) acc[i][j] = (f32x4){0.f, 0.f, 0.f, 0.f};

    for (int k0 = 0; k0 < D_; k0 += 32) {
        __syncthreads();
#pragma unroll
        for (int it = 0; it < 4; ++it) {
            int idx = t + it * 256;
            int row = idx >> 3;
            int c   = idx & 7;
            float4 v = *reinterpret_cast<const float4*>(
                &A[(size_t)(m0 + row) * D_ + k0 + c * 4]);
            f16x4 h4 = {(f16)v.x, (f16)v.y, (f16)v.z, (f16)v.w};
            *reinterpret_cast<f16x4*>(&Ah[row * 40 + c * 4]) = h4;
        }
#pragma unroll
        for (int it = 0; it < 2; ++it) {
            int idx = t + it * 256;
            int row = idx >> 2;
            int c   = idx & 3;
            size_t gsrc = (size_t)(n0 + row) * D_ + k0 + c * 8;
            *reinterpret_cast<f16x8*>(&Wh[row * 40 + c * 8]) =
                *reinterpret_cast<const f16x8*>(&wh_g[gsrc]);
            *reinterpret_cast<f16x8*>(&Wl[row * 40 + c * 8]) =
                *reinterpret_cast<const f16x8*>(&wl_g[gsrc]);
        }
        __syncthreads();

        f16x8 ah[4], whf[4], wlf[4];
#pragma unroll
        for (int m = 0; m < 4; ++m) {
            int row = wrow * 64 + m * 16 + lo;
            ah[m] = *reinterpret_cast<const f16x8*>(&Ah[row * 40 + g * 8]);
        }
#pragma unroll
        for (int n = 0; n < 4; ++n) {
            int row = wcol * 64 + n * 16 + lo;
            whf[n] = *reinterpret_cast<const f16x8*>(&Wh[row * 40 + g * 8]);
            wlf[n] = *reinterpret_cast<const f16x8*>(&Wl[row * 40 + g * 8]);
        }
#pragma unroll
        for (int m = 0; m < 4; ++m)
#pragma unroll
            for (int n = 0; n < 4; ++n) {
                acc[m][n] = MFMA16(ah[m], whf[n], acc[m][n]);
                acc[m][n] = MFMA16(ah[m], wlf[n], acc[m][n]);
            }
    }

    float bias_v[4];
#pragma unroll
    for (int n = 0; n < 4; ++n) bias_v[n] = bias[n0 + wcol * 64 + n * 16 + lo];

    if (z < 2) {
        f16* hd = (z == 0) ? qh : kh;
#pragma unroll
        for (int n = 0; n < 4; ++n) {
            int col = n0 + wcol * 64 + n * 16 + lo;
            int hh  = col >> 6;
            int dh  = col & 63;
#pragma unroll
            for (int m = 0; m < 4; ++m)
#pragma unroll
                for (int r = 0; r < 4; ++r) {
                    int grow = m0 + wrow * 64 + m * 16 + g * 4 + r;
                    int bb   = grow >> 11;
                    int ss   = grow & (S_ - 1);
                    float val = acc[m][n][r] + bias_v[n];
                    size_t base = ((size_t)(bb * H_ + hh) * S_ + ss) * DH_ + dh;
                    hd[base] = (f16)val;
                }
        }
    } else {
        __syncthreads();
        f16* vtile = SM + w * 4608;           // [64][72]
#pragma unroll
        for (int n = 0; n < 4; ++n)
#pragma unroll
            for (int m = 0; m < 4; ++m)
#pragma unroll
                for (int r = 0; r < 4; ++r) {
                    int c = m * 16 + g * 4 + r;
                    vtile[(n * 16 + lo) * 72 + permc(c)] =
                        (f16)(acc[m][n][r] + bias_v[n]);
                }
        int bb = m0 >> 11;
        int s_base = (m0 & (S_ - 1)) + wrow * 64;
#pragma unroll
        for (int it = 0; it < 8; ++it) {
            int idx = lane + it * 64;
            int cl  = idx >> 3;
            int mc  = idx & 7;
            f16x8 vv = *reinterpret_cast<const f16x8*>(&vtile[cl * 72 + mc * 8]);
            int col = n0 + wcol * 64 + cl;
            int hh  = col >> 6;
            int dh  = col & 63;
            *reinterpret_cast<f16x8*>(
                &vt[((size_t)(bb * H_ + hh) * DH_ + dh) * S_ + s_base + mc * 8]) = vv;
        }
    }
}

// ---------------------------------------------------------------------------
// MFMA flash attention, v9: exact R9 skeleton (2 barriers/iter, reg-staged
// K/V/PE, LDS PE ring, no setprio) + PE fragment REGISTER ROTATION: band
// shifts -32/iter so tiles tau=2,3 of iter i+1 are tiles tau=0,1 of iter i.
// Only 2 fresh PE tiles read from LDS per iter (4 b128 instead of 8).
// ---------------------------------------------------------------------------
__global__ __launch_bounds__(256) void attn_mfma_kernel(
    const f16* __restrict__ qh, const f16* __restrict__ kh,
    const f16* __restrict__ vt, const f16* __restrict__ pe,
    const float* __restrict__ gm, const float* __restrict__ am,
    float* __restrict__ out)
{
    __shared__ __align__(16) f16 Kh[32 * 72];
    __shared__ __align__(16) f16 Vt[64 * 40];
    __shared__ __align__(16) f16 PE[256 * 72];
    __shared__ __align__(16) f16 Pl[4 * 32 * 40];

    const int t    = threadIdx.x;
    const int w    = t >> 6;
    const int lane = t & 63;
    const int lo   = lane & 15;
    const int g    = lane >> 4;
    const int bh   = blockIdx.y;
    const int b    = bh >> 4;
    const int h    = bh & 15;
    const int l0   = blockIdx.x * 128;
    const int lw   = l0 + w * 32;

    const int krow = t >> 3, kc8 = (t & 7) * 8;       // K & PE staging pattern
    const int vrow = t >> 2, vc8 = (t & 3) * 8;       // V staging pattern

    // Q fragments for both 16-row subs
    f16x8 qf[2][2];
#pragma unroll
    for (int sub = 0; sub < 2; ++sub) {
        size_t qbase = ((size_t)bh * S_ + lw + sub * 16 + lo) * DH_ + g * 8;
        qf[sub][0] = *reinterpret_cast<const f16x8*>(qh + qbase);
        qf[sub][1] = *reinterpret_cast<const f16x8*>(qh + qbase + 32);
    }

    // PE prefill: logical rows [l0+2048, l0+2176) (128 rows, clamped)
#pragma unroll
    for (int i = 0; i < 4; ++i) {
        int idx = t + i * 256;
        int row = idx >> 3, c8 = (idx & 7) * 8;
        int logical = l0 + 2048 + row;
        int gl = logical > 4095 ? 4095 : logical;
        *reinterpret_cast<f16x8*>(PE + (size_t)(logical & 255) * 72 + c8) =
            *reinterpret_cast<const f16x8*>(pe + (size_t)gl * DH_ + c8);
    }

    // iter-0 staging loads (pereg covers rows [l0+2016, l0+2048))
    f16x8 kreg, vreg, pereg;
    kreg  = *reinterpret_cast<const f16x8*>(kh + ((size_t)bh * S_ + krow) * DH_ + kc8);
    vreg  = *reinterpret_cast<const f16x8*>(vt + ((size_t)bh * DH_ + vrow) * S_ + vc8);
    pereg = *reinterpret_cast<const f16x8*>(pe + (size_t)(l0 + 2016 + krow) * DH_ + kc8);

    f32x4 o[2][4];
#pragma unroll
    for (int sub = 0; sub < 2; ++sub)
#pragma unroll
        for (int n = 0; n < 4; ++n) o[sub][n] = (f32x4){0.f, 0.f, 0.f, 0.f};
    float l_part[2][4] = {{0.f, 0.f, 0.f, 0.f}, {0.f, 0.f, 0.f, 0.f}};

    f16* Pw = Pl + w * 32 * 40;

    // rotating PE fragments (tau tiles 0..3; a = cols 0-31, b = cols 32-63)
    f16x8 pe0a, pe0b, pe1a, pe1b, pe2a, pe2b, pe3a, pe3b;

    for (int r0 = 0; r0 < S_; r0 += 32) {
        const int g0 = l0 + 2016 - r0;
        // ---- write staged regs to LDS ----
        *reinterpret_cast<f16x8*>(Kh + krow * 72 + kc8) = kreg;
        *reinterpret_cast<f16x8*>(Vt + vrow * 40 + vc8) = vreg;
        *reinterpret_cast<f16x8*>(PE + (size_t)((g0 + krow) & 255) * 72 + kc8) = pereg;
        __syncthreads();

        // issue next tile's staging loads (hide under compute)
        if (r0 + 32 < S_) {
            int r0n = r0 + 32;
            kreg  = *reinterpret_cast<const f16x8*>(
                kh + ((size_t)bh * S_ + r0n + krow) * DH_ + kc8);
            vreg  = *reinterpret_cast<const f16x8*>(
                vt + ((size_t)bh * DH_ + vrow) * S_ + r0n + vc8);
            pereg = *reinterpret_cast<const f16x8*>(
                pe + (size_t)(g0 - 32 + krow) * DH_ + kc8);
        }
        float am0 = am[b * S_ + r0 + lo];
        float am1 = am[b * S_ + r0 + 16 + lo];

        // ---- PE tile rotation: tiles 2,3 <- old 0,1; fresh reads for 0,1 ----
        {
            int pr0 = (g0 + w * 32 + lo) & 255;
            int pr1 = (g0 + w * 32 + 16 + lo) & 255;
            f16x8 n0a = *reinterpret_cast<const f16x8*>(PE + (size_t)pr0 * 72 + g * 8);
            f16x8 n0b = *reinterpret_cast<const f16x8*>(PE + (size_t)pr0 * 72 + 32 + g * 8);
            f16x8 n1a = *reinterpret_cast<const f16x8*>(PE + (size_t)pr1 * 72 + g * 8);
            f16x8 n1b = *reinterpret_cast<const f16x8*>(PE + (size_t)pr1 * 72 + 32 + g * 8);
            if (r0 == 0) {
                int pr2 = (g0 + w * 32 + 32 + lo) & 255;
                int pr3 = (g0 + w * 32 + 48 + lo) & 255;
                pe2a = *reinterpret_cast<const f16x8*>(PE + (size_t)pr2 * 72 + g * 8);
                pe2b = *reinterpret_cast<const f16x8*>(PE + (size_t)pr2 * 72 + 32 + g * 8);
                pe3a = *reinterpret_cast<const f16x8*>(PE + (size_t)pr3 * 72 + g * 8);
                pe3b = *reinterpret_cast<const f16x8*>(PE + (size_t)pr3 * 72 + 32 + g * 8);
            } else {
                pe2a = pe0a; pe2b = pe0b;
                pe3a = pe1a; pe3b = pe1b;
            }
            pe0a = n0a; pe0b = n0b;
            pe1a = n1a; pe1b = n1b;
        }

        // ---- QK^T: K frags shared across subs ----
        f32x4 sc[2][2];
        sc[0][0] = (f32x4){0.f,0.f,0.f,0.f}; sc[0][1] = (f32x4){0.f,0.f,0.f,0.f};
        sc[1][0] = (f32x4){0.f,0.f,0.f,0.f}; sc[1][1] = (f32x4){0.f,0.f,0.f,0.f};
#pragma unroll
        for (int u = 0; u < 2; ++u)
#pragma unroll
            for (int s = 0; s < 2; ++s) {
                f16x8 kb = *reinterpret_cast<const f16x8*>(
                    Kh + (u * 16 + lo) * 72 + s * 32 + g * 8);
                sc[0][u] = MFMA16(qf[0][s], kb, sc[0][u]);
                sc[1][u] = MFMA16(qf[1][s], kb, sc[1][u]);
            }
        // ---- bias band from rotated register tiles ----
        f32x4 mmA[3], mmB[3];
#pragma unroll
        for (int i = 0; i < 3; ++i) {
            mmA[i] = (f32x4){0.f,0.f,0.f,0.f};
            mmB[i] = (f32x4){0.f,0.f,0.f,0.f};
        }
        mmA[0] = MFMA16(qf[0][0], pe0a, mmA[0]);
        mmA[0] = MFMA16(qf[0][1], pe0b, mmA[0]);
        mmA[1] = MFMA16(qf[0][0], pe1a, mmA[1]);
        mmA[1] = MFMA16(qf[0][1], pe1b, mmA[1]);
        mmB[0] = MFMA16(qf[1][0], pe1a, mmB[0]);
        mmB[0] = MFMA16(qf[1][1], pe1b, mmB[0]);
        mmA[2] = MFMA16(qf[0][0], pe2a, mmA[2]);
        mmA[2] = MFMA16(qf[0][1], pe2b, mmA[2]);
        mmB[1] = MFMA16(qf[1][0], pe2a, mmB[1]);
        mmB[1] = MFMA16(qf[1][1], pe2b, mmB[1]);
        mmB[2] = MFMA16(qf[1][0], pe3a, mmB[2]);
        mmB[2] = MFMA16(qf[1][1], pe3b, mmB[2]);

        // ---- scores + gather + fixed-shift exp + packed P publish ----
#pragma unroll
        for (int sub = 0; sub < 2; ++sub) {
            float gm0[4], gm1[4];
#pragma unroll
            for (int r = 0; r < 4; ++r) {
                size_t grow = (size_t)(lw + sub * 16 + g * 4 + r) * S_ + r0;
                gm0[r] = gm[grow + lo];
                gm1[r] = gm[grow + 16 + lo];
            }
#pragma unroll
            for (int r = 0; r < 4; ++r) {
                int dl = g * 4 + r;
                int pl_ = (dl + 15 - lo) & 15;
                bool cond = pl_ < dl;
                float v0, v1;
                if (sub == 0) {
                    v0 = cond ? mmA[2][r] : mmA[1][r];
                    v1 = cond ? mmA[1][r] : mmA[0][r];
                } else {
                    v0 = cond ? mmB[2][r] : mmB[1][r];
                    v1 = cond ? mmB[1][r] : mmB[0][r];
                }
                union { fp16x2 hv; int iv; } pk, gk;
                pk.hv = __builtin_amdgcn_cvt_pkrtz(v0, v1);
                int src = (lane & 48) | pl_;
                gk.iv = __shfl(pk.iv, src, 64);
                float s0 = (sc[sub][0][r] + (float)gk.hv[0]) * 0.125f * gm0[r] + am0;
                float s1 = (sc[sub][1][r] + (float)gk.hv[1]) * 0.125f * gm1[r] + am1;
                float p0 = __expf(s0 - 6.f);
                float p1 = __expf(s1 - 6.f);
                l_part[sub][r] += p0 + p1;
                union { f16 h2[2]; int iv; } pp;
                pp.h2[0] = (f16)p0;
                pp.h2[1] = (f16)p1;
                *reinterpret_cast<int*>(Pw + (sub * 16 + dl) * 40 + 2 * lo) = pp.iv;
            }
        }
        // ---- PV: V frags shared across subs ----
        f16x8 pa0 = *reinterpret_cast<const f16x8*>(Pw + lo * 40 + g * 8);
        f16x8 pa1 = *reinterpret_cast<const f16x8*>(Pw + (16 + lo) * 40 + g * 8);
#pragma unroll
        for (int n = 0; n < 4; ++n) {
            f16x8 vb = *reinterpret_cast<const f16x8*>(Vt + (n * 16 + lo) * 40 + g * 8);
            o[0][n] = MFMA16(pa0, vb, o[0][n]);
            o[1][n] = MFMA16(pa1, vb, o[1][n]);
        }
        __syncthreads();    // all waves done reading LDS before next ds_write
    }

    // ---- epilogue ----
#pragma unroll
    for (int sub = 0; sub < 2; ++sub)
#pragma unroll
        for (int r = 0; r < 4; ++r) {
            float ls = l_part[sub][r];
            ls += DPPF(ls, 0xB1);
            ls += DPPF(ls, 0x4E);
            ls += DPPF(ls, 0x141);
            ls += DPPF(ls, 0x140);
            float inv = 1.f / ls;
            int l = lw + sub * 16 + g * 4 + r;
#pragma unroll
            for (int n = 0; n < 4; ++n)
                out[((size_t)b * S_ + l) * D_ + h * DH_ + n * 16 + lo] = o[sub][n][r] * inv;
        }
}

// ---------------------------------------------------------------------------
extern "C" void kernel_launch(void* const* d_in, const int* in_sizes, int n_in,
                              void* d_out, int out_size, void* d_ws, size_t ws_size,
                              hipStream_t stream)
{
    const float* hs    = (const float*)d_in[0];
    const float* amask = (const float*)d_in[1];
    const float* gmask = (const float*)d_in[2];
    const float* Wq    = (const float*)d_in[3];
    const float* bq    = (const float*)d_in[4];
    const float* Wk    = (const float*)d_in[5];
    const float* bk    = (const float*)d_in[6];
    const float* Wv    = (const float*)d_in[7];
    const float* bv    = (const float*)d_in[8];
    const float* dist  = (const float*)d_in[9];
    float* out = (float*)d_out;

    const size_t per = (size_t)B_ * H_ * S_ * DH_;   // 4M f16
    f16* qh  = (f16*)d_ws;
    f16* kh  = qh + per;
    f16* vt  = kh + per;
    f16* wht = vt + per;                              // 3M f16
    f16* wlt = wht + (size_t)3 * D_ * D_;             // 3M f16
    f16* pe  = wlt + (size_t)3 * D_ * D_;             // 4096*64 f16

    split_w_kernel<<<dim3(16, 16, 3), 256, 0, stream>>>(Wq, Wk, Wv, wht, wlt);
    pe_convert_kernel<<<dim3(1024), 256, 0, stream>>>(dist, pe);

    dim3 g1((B_ * S_) / 128, D_ / 128, 3);
    mfma_proj_kernel<<<g1, 256, 0, stream>>>(hs, wht, wlt, bq, bk, bv,
                                             qh, kh, vt);

    dim3 g2(S_ / 128, B_ * H_);
    attn_mfma_kernel<<<g2, 256, 0, stream>>>(qh, kh, vt, pe,
                                             gmask, amask, out);
}